// Round 3
// baseline (53.340 us; speedup 1.0000x reference)
//
#include <hip/hip_runtime.h>
#include <math.h>

#define TT 4096
#define DD 1024
#define NSPAN 8192
#define MW 30
#define WEMB 20
#define VECW (4*DD + WEMB)   // 4116 floats per span row

typedef float nf4 __attribute__((ext_vector_type(4)));

static __device__ __forceinline__ void fma4(float4& acc, const float w, const float4 v) {
    acc.x = fmaf(w, v.x, acc.x); acc.y = fmaf(w, v.y, acc.y);
    acc.z = fmaf(w, v.z, acc.z); acc.w = fmaf(w, v.w, acc.w);
}
static __device__ __forceinline__ void add4(float4& acc, const float4 v) {
    acc.x += v.x; acc.y += v.y; acc.z += v.z; acc.w += v.w;
}
static __device__ __forceinline__ void nstore(const float4 v, float* p) {
    nf4 t = { v.x, v.y, v.z, v.w };
    __builtin_nontemporal_store(t, (nf4*)p);
}

// ---- kernel 1: fused {token_attn} + {counting-sort by b} in one launch ----
// block 0            : hist + scan + scatter (all in LDS, 1024 threads)
// blocks 1..TT/4     : token_attn for 4 tokens each (4 x 256-lane float4 dot)
__global__ void __launch_bounds__(1024) prep_kernel(
        const float* __restrict__ x,
        const float* __restrict__ attn_w,
        const float* __restrict__ attn_b,
        const int* __restrict__ bptr,
        float* __restrict__ ta,
        int* __restrict__ perm) {
    const int tid = threadIdx.x;
    if (blockIdx.x == 0) {
        __shared__ int h[TT];          // histogram, then running offsets
        __shared__ int wsum[16];
        #pragma unroll
        for (int k = 0; k < 4; ++k) h[tid * 4 + k] = 0;
        __syncthreads();
        #pragma unroll
        for (int k = 0; k < NSPAN / 1024; ++k)
            atomicAdd(&h[bptr[k * 1024 + tid]], 1);
        __syncthreads();
        const int v0 = h[tid*4+0], v1 = h[tid*4+1], v2 = h[tid*4+2], v3 = h[tid*4+3];
        const int s = v0 + v1 + v2 + v3;
        const int lane = tid & 63;
        int incl = s;
        #pragma unroll
        for (int off = 1; off < 64; off <<= 1) {
            int t = __shfl_up(incl, off);
            if (lane >= off) incl += t;
        }
        if (lane == 63) wsum[tid >> 6] = incl;
        __syncthreads();
        if (tid < 16) {   // scan the 16 wave totals within wave 0
            int ws = wsum[tid];
            #pragma unroll
            for (int off = 1; off < 16; off <<= 1) {
                int t = __shfl_up(ws, off);
                if (tid >= off) ws += t;
            }
            wsum[tid] = ws;
        }
        __syncthreads();
        const int waveoff = (tid >> 6) == 0 ? 0 : wsum[(tid >> 6) - 1];
        int excl = waveoff + (incl - s);
        h[tid*4+0] = excl;  excl += v0;
        h[tid*4+1] = excl;  excl += v1;
        h[tid*4+2] = excl;  excl += v2;
        h[tid*4+3] = excl;
        __syncthreads();
        #pragma unroll
        for (int k = 0; k < NSPAN / 1024; ++k) {
            const int n = k * 1024 + tid;
            const int pos = atomicAdd(&h[bptr[n]], 1);
            perm[pos] = n;
        }
    } else {
        const int sub = tid >> 8;          // 0..3: which of 4 tokens
        const int l   = tid & 255;         // 0..255: float4 lane
        const int t   = (blockIdx.x - 1) * 4 + sub;
        const float4 v = ((const float4*)(x + (size_t)t * DD))[l];
        const float4 w = ((const float4*)attn_w)[l];
        float s = v.x * w.x + v.y * w.y + v.z * w.z + v.w * w.w;
        #pragma unroll
        for (int off = 32; off > 0; off >>= 1) s += __shfl_down(s, off);
        __shared__ float part[16];
        if ((tid & 63) == 0) part[tid >> 6] = s;   // wave id = 4*sub + (l>>6)
        __syncthreads();
        if (l == 0)
            ta[t] = part[sub*4] + part[sub*4+1] + part[sub*4+2] + part[sub*4+3]
                  + attn_b[0];
    }
}

// ---- kernel 2: one WAVE per (sorted) span; softmax from ta, no LDS/syncs ----
// lane l owns float4 slices {l, 64+l, 128+l, 192+l} of every D-row, so each
// load/store covers a contiguous 1 KiB (64 lanes x 16 B).
// Softmax over ta[b..e] is computed ONCE per span across lanes (len <= 30):
// |ta| <= ~3 so no max-subtraction needed; normalization deferred to epilogue.
// Per-row weight is then a single __shfl broadcast -> short per-row chain.
// Section float offsets in a span row (VECW=4116):
//   b_vec 0 | e_vec DD | width_emb 2*DD | head_emb 2*DD+WEMB | span_avg 3*DD+WEMB
__global__ void __launch_bounds__(256, 4) span_kernel(
        const float* __restrict__ x,
        const int* __restrict__ bptr,
        const int* __restrict__ eptr,
        const float* __restrict__ embed_w,
        const float* __restrict__ ta,
        const int* __restrict__ perm,
        float* __restrict__ out) {
    const int tid = threadIdx.x;
    const int wv  = tid >> 6;          // wave 0..3: which span of this block
    const int l   = tid & 63;          // lane
    // XCD-chunked swizzle: XCD k gets a contiguous 1024-run of sorted spans
    // -> ~512-token window (~2 MB of x) resident in its 4 MB L2.
    const int blk  = (blockIdx.x & 7) * (NSPAN / 4 / 8) + (blockIdx.x >> 3);
    const int spos = blk * 4 + wv;
    const int n    = perm[spos];
    const int b     = bptr[n];
    const int e_raw = eptr[n];
    const int e     = min(e_raw, TT - 1);
    const int width = e_raw - b;
    const int len   = e - b + 1;       // 1..MW

    // wave softmax over ta[b..e]: lane i holds unnormalized exp; sum via xor-shuffles
    float ex = 0.0f;
    if (l < len) ex = exp2f(ta[b + l] * 1.44269504f);
    float ssum = ex;
    ssum += __shfl_xor(ssum, 32); ssum += __shfl_xor(ssum, 16);
    ssum += __shfl_xor(ssum, 8);  ssum += __shfl_xor(ssum, 4);
    ssum += __shfl_xor(ssum, 2);  ssum += __shfl_xor(ssum, 1);

    const float4* xr = (const float4*)(x + (size_t)b * DD);
    float* orow = out + (size_t)n * VECW;

    // row b (current regs c*)
    float4 c0 = xr[l], c1 = xr[64 + l], c2 = xr[128 + l], c3 = xr[192 + l];
    nstore(c0, orow + 4*l);                    // b_vec
    nstore(c1, orow + 4*(64 + l));
    nstore(c2, orow + 4*(128 + l));
    nstore(c3, orow + 4*(192 + l));

    float4 h0 = {0,0,0,0}, h1 = {0,0,0,0}, h2 = {0,0,0,0}, h3 = {0,0,0,0};
    float4 a0 = {0,0,0,0}, a1 = {0,0,0,0}, a2 = {0,0,0,0}, a3 = {0,0,0,0};

    // pipelined: issue loads of row i while row i-1 accumulates
    for (int i = 1; i < len; ++i) {
        const float4* row = xr + (size_t)i * 256;
        const float4 n0 = row[l], n1 = row[64 + l], n2 = row[128 + l], n3 = row[192 + l];
        const float w = __shfl(ex, i - 1);
        fma4(h0, w, c0); fma4(h1, w, c1); fma4(h2, w, c2); fma4(h3, w, c3);
        add4(a0, c0); add4(a1, c1); add4(a2, c2); add4(a3, c3);
        c0 = n0; c1 = n1; c2 = n2; c3 = n3;
    }
    {
        const float w = __shfl(ex, len - 1);   // last row (== row e)
        fma4(h0, w, c0); fma4(h1, w, c1); fma4(h2, w, c2); fma4(h3, w, c3);
        add4(a0, c0); add4(a1, c1); add4(a2, c2); add4(a3, c3);
    }

    float* esec = orow + DD;                   // e_vec
    nstore(c0, esec + 4*l);
    nstore(c1, esec + 4*(64 + l));
    nstore(c2, esec + 4*(128 + l));
    nstore(c3, esec + 4*(192 + l));

    const float invs = 1.0f / ssum;
    const float invl = 1.0f / (float)len;
    h0.x *= invs; h0.y *= invs; h0.z *= invs; h0.w *= invs;
    h1.x *= invs; h1.y *= invs; h1.z *= invs; h1.w *= invs;
    h2.x *= invs; h2.y *= invs; h2.z *= invs; h2.w *= invs;
    h3.x *= invs; h3.y *= invs; h3.z *= invs; h3.w *= invs;
    a0.x *= invl; a0.y *= invl; a0.z *= invl; a0.w *= invl;
    a1.x *= invl; a1.y *= invl; a1.z *= invl; a1.w *= invl;
    a2.x *= invl; a2.y *= invl; a2.z *= invl; a2.w *= invl;
    a3.x *= invl; a3.y *= invl; a3.z *= invl; a3.w *= invl;

    float* hsec = orow + 2*DD + WEMB;          // head_emb
    nstore(h0, hsec + 4*l);
    nstore(h1, hsec + 4*(64 + l));
    nstore(h2, hsec + 4*(128 + l));
    nstore(h3, hsec + 4*(192 + l));
    float* asec = orow + 3*DD + WEMB;          // span_avg
    nstore(a0, asec + 4*l);
    nstore(a1, asec + 4*(64 + l));
    nstore(a2, asec + 4*(128 + l));
    nstore(a3, asec + 4*(192 + l));

    if (l < 5) {                               // width_emb: 5 float4 = 20 floats
        const float4 we = ((const float4*)(embed_w + width * WEMB))[l];
        nstore(we, orow + 2*DD + 4*l);
    }
    if (l == 63)
        __builtin_nontemporal_store((float)width, out + (size_t)NSPAN * VECW + n);
}

extern "C" void kernel_launch(void* const* d_in, const int* in_sizes, int n_in,
                              void* d_out, int out_size, void* d_ws, size_t ws_size,
                              hipStream_t stream) {
    const float* x       = (const float*)d_in[0];  // [1,T,D]
    const int*   b       = (const int*)  d_in[1];  // [1,N]
    const int*   e       = (const int*)  d_in[2];  // [1,N]
    const float* embed_w = (const float*)d_in[4];  // [MW,WEMB]
    const float* attn_w  = (const float*)d_in[5];  // [D,1]
    const float* attn_b  = (const float*)d_in[6];  // [1]
    float* out = (float*)d_out;

    // workspace layout
    float* ta   = (float*)d_ws;                    // TT floats
    int*   perm = (int*)(ta + TT);                 // NSPAN ints

    prep_kernel<<<1 + TT/4, 1024, 0, stream>>>(x, attn_w, attn_b, b, ta, perm);
    span_kernel<<<NSPAN / 4, 256, 0, stream>>>(x, b, e, embed_w, ta, perm, out);
}

// Round 4
// 52.465 us; speedup vs baseline: 1.0167x; 1.0167x over previous
//
#include <hip/hip_runtime.h>
#include <math.h>

#define TT 4096
#define DD 1024
#define NSPAN 8192
#define MW 30
#define WEMB 20
#define VECW (4*DD + WEMB)   // 4116 floats per span row

typedef float nf4 __attribute__((ext_vector_type(4)));

static __device__ __forceinline__ float dot4(const float4 a, const float4 b) {
    return fmaf(a.w, b.w, fmaf(a.z, b.z, fmaf(a.y, b.y, a.x * b.x)));
}
static __device__ __forceinline__ void nstore(const float4 v, float* p) {
    nf4 t = { v.x, v.y, v.z, v.w };
    __builtin_nontemporal_store(t, (nf4*)p);
}

// ---- kernel 1: fused {counting-sort by b} + {token_attn} ----
// block 0        : hist + scan + scatter (all in LDS, 1024 threads)
// blocks 1..256  : token_attn, 1 token per wave (16 tokens/block), no LDS/sync
__global__ void __launch_bounds__(1024) prep_kernel(
        const float* __restrict__ x,
        const float* __restrict__ attn_w,
        const float* __restrict__ attn_b,
        const int* __restrict__ bptr,
        float* __restrict__ ta,
        int* __restrict__ perm) {
    const int tid = threadIdx.x;
    if (blockIdx.x == 0) {
        __shared__ int h[TT];          // histogram, then running offsets
        __shared__ int wsum[16];
        #pragma unroll
        for (int k = 0; k < 4; ++k) h[tid * 4 + k] = 0;
        __syncthreads();
        #pragma unroll
        for (int k = 0; k < NSPAN / 1024; ++k)
            atomicAdd(&h[bptr[k * 1024 + tid]], 1);
        __syncthreads();
        const int v0 = h[tid*4+0], v1 = h[tid*4+1], v2 = h[tid*4+2], v3 = h[tid*4+3];
        const int s = v0 + v1 + v2 + v3;
        const int lane = tid & 63;
        int incl = s;
        #pragma unroll
        for (int off = 1; off < 64; off <<= 1) {
            int t = __shfl_up(incl, off);
            if (lane >= off) incl += t;
        }
        if (lane == 63) wsum[tid >> 6] = incl;
        __syncthreads();
        if (tid < 16) {   // scan the 16 wave totals within wave 0
            int ws = wsum[tid];
            #pragma unroll
            for (int off = 1; off < 16; off <<= 1) {
                int t = __shfl_up(ws, off);
                if (tid >= off) ws += t;
            }
            wsum[tid] = ws;
        }
        __syncthreads();
        const int waveoff = (tid >> 6) == 0 ? 0 : wsum[(tid >> 6) - 1];
        int excl = waveoff + (incl - s);
        h[tid*4+0] = excl;  excl += v0;
        h[tid*4+1] = excl;  excl += v1;
        h[tid*4+2] = excl;  excl += v2;
        h[tid*4+3] = excl;
        __syncthreads();
        #pragma unroll
        for (int k = 0; k < NSPAN / 1024; ++k) {
            const int n = k * 1024 + tid;
            const int pos = atomicAdd(&h[bptr[n]], 1);
            perm[pos] = n;
        }
    } else {
        // one token per wave: 4 coalesced 1 KiB loads + in-wave reduce
        const int wv = tid >> 6;           // 0..15
        const int l  = tid & 63;
        const int t  = (blockIdx.x - 1) * 16 + wv;
        const float4* xr = (const float4*)(x + (size_t)t * DD);
        const float4* aw = (const float4*)attn_w;
        const float4 v0 = xr[l], v1 = xr[64 + l], v2 = xr[128 + l], v3 = xr[192 + l];
        const float4 w0 = aw[l], w1 = aw[64 + l], w2 = aw[128 + l], w3 = aw[192 + l];
        float s = (dot4(v0, w0) + dot4(v1, w1)) + (dot4(v2, w2) + dot4(v3, w3));
        s += __shfl_xor(s, 32); s += __shfl_xor(s, 16);
        s += __shfl_xor(s, 8);  s += __shfl_xor(s, 4);
        s += __shfl_xor(s, 2);  s += __shfl_xor(s, 1);
        if (l == 0) ta[t] = s + attn_b[0];
    }
}

// ---- kernel 2: one block per (sorted) span — NO barriers, NO LDS ----
// Each of the 4 waves redundantly computes the span softmax from ta in-wave
// (len <= 30 <= 64 lanes; |ta| small so no max-subtraction; normalization
// deferred to the epilogue). Per-row weight is a uniform-index __shfl.
// The row-b load is issued BEFORE the softmax so ta latency hides under it.
__global__ void __launch_bounds__(256, 8) span_kernel(
        const float* __restrict__ x,
        const int* __restrict__ bptr,
        const int* __restrict__ eptr,
        const float* __restrict__ embed_w,
        const float* __restrict__ ta,
        const int* __restrict__ perm,
        float* __restrict__ out) {
    const int tid = threadIdx.x;           // 256 threads, one float4 of D each
    const int l   = tid & 63;
    // XCD-chunked swizzle: block i -> sorted position (i%8)*1024 + i/8,
    // so each XCD's resident blocks cover a tight, contiguous token window.
    const int spos = (blockIdx.x & 7) * (NSPAN / 8) + (blockIdx.x >> 3);
    const int n    = perm[spos];
    const int b     = bptr[n];
    const int e_raw = eptr[n];
    const int e     = min(e_raw, TT - 1);
    const int width = e_raw - b;
    const int len   = e - b + 1;           // 1..MW

    const float4* xrow = (const float4*)(x + (size_t)b * DD);
    float* orow = out + (size_t)n * VECW;

    // issue row-b load first; softmax latency hides under it
    float4 v = xrow[tid];

    // in-wave softmax over ta[b..e] (replicated across the 4 waves)
    float ex = (l < len) ? exp2f(ta[b + l] * 1.44269504f) : 0.0f;
    float ssum = ex;
    ssum += __shfl_xor(ssum, 32); ssum += __shfl_xor(ssum, 16);
    ssum += __shfl_xor(ssum, 8);  ssum += __shfl_xor(ssum, 4);
    ssum += __shfl_xor(ssum, 2);  ssum += __shfl_xor(ssum, 1);

    nstore(v, orow + 4*tid);               // b_vec

    const float w0 = __shfl(ex, 0);
    float4 acc_h = make_float4(w0 * v.x, w0 * v.y, w0 * v.z, w0 * v.w);
    float4 acc_a = v;
    // pipelined: load row i while row i-1's accumulate runs
    for (int i = 1; i < len; ++i) {
        const float4 nv = xrow[(size_t)i * 256 + tid];
        const float w = __shfl(ex, i);
        acc_h.x = fmaf(w, nv.x, acc_h.x); acc_h.y = fmaf(w, nv.y, acc_h.y);
        acc_h.z = fmaf(w, nv.z, acc_h.z); acc_h.w = fmaf(w, nv.w, acc_h.w);
        acc_a.x += nv.x; acc_a.y += nv.y; acc_a.z += nv.z; acc_a.w += nv.w;
        v = nv;
    }
    nstore(v, orow + DD + 4*tid);          // e_vec (row e)

    const float invs = 1.0f / ssum;
    const float invl = 1.0f / (float)len;
    acc_h.x *= invs; acc_h.y *= invs; acc_h.z *= invs; acc_h.w *= invs;
    acc_a.x *= invl; acc_a.y *= invl; acc_a.z *= invl; acc_a.w *= invl;
    nstore(acc_h, orow + 2*DD + WEMB + 4*tid);   // head_emb
    nstore(acc_a, orow + 3*DD + WEMB + 4*tid);   // span_avg

    if (tid < 5) {                         // width_emb: 5 float4 = 20 floats
        const float4 we = ((const float4*)(embed_w + width * WEMB))[tid];
        nstore(we, orow + 2*DD + 4*tid);
    }
    if (tid == 0)
        __builtin_nontemporal_store((float)width, out + (size_t)NSPAN * VECW + n);
}

extern "C" void kernel_launch(void* const* d_in, const int* in_sizes, int n_in,
                              void* d_out, int out_size, void* d_ws, size_t ws_size,
                              hipStream_t stream) {
    const float* x       = (const float*)d_in[0];  // [1,T,D]
    const int*   b       = (const int*)  d_in[1];  // [1,N]
    const int*   e       = (const int*)  d_in[2];  // [1,N]
    const float* embed_w = (const float*)d_in[4];  // [MW,WEMB]
    const float* attn_w  = (const float*)d_in[5];  // [D,1]
    const float* attn_b  = (const float*)d_in[6];  // [1]
    float* out = (float*)d_out;

    // workspace layout
    float* ta   = (float*)d_ws;                    // TT floats
    int*   perm = (int*)(ta + TT);                 // NSPAN ints

    prep_kernel<<<1 + TT/16, 1024, 0, stream>>>(x, attn_w, attn_b, b, ta, perm);
    span_kernel<<<NSPAN, 256, 0, stream>>>(x, b, e, embed_w, ta, perm, out);
}